// Round 5
// baseline (1436.169 us; speedup 1.0000x reference)
//
#include <hip/hip_runtime.h>
#include <hip/hip_bf16.h>
#include <math.h>

// Problem constants
#define KF   7      // frames / groups
#define BB_  4      // batch
#define CC_  64     // channels per frame
#define HH   96
#define WW   96
#define HWSZ 9216   // 96*96
#define HEAD 256
#define CH2  448    // channels-last width of X2

typedef __bf16 bf16x8 __attribute__((ext_vector_type(8)));
typedef __bf16 bf16x4 __attribute__((ext_vector_type(4)));
typedef float  f32x4  __attribute__((ext_vector_type(4)));
typedef _Float16 half4v __attribute__((ext_vector_type(4)));

// ---------------------------------------------------------------------------
// features (K,B,C,H,W) fp32 -> X2[b][h][w][g*64+c] bf16 (channels-last)
// ---------------------------------------------------------------------------
__global__ __launch_bounds__(256) void cvt_feat(const float* __restrict__ feat,
                                                __bf16* __restrict__ X2) {
    __shared__ float sT[96][65];
    const int h = blockIdx.x;
    const int n = blockIdx.y;          // g*4+b
    const int g = n >> 2, b = n & 3;
    const int t = threadIdx.x;
    const float* src = feat + (size_t)n * 64 * HWSZ + h * WW;
    for (int e = t; e < 6144; e += 256) {
        int c = e / 96, w = e - c * 96;
        sT[w][c] = src[(size_t)c * HWSZ + w];
    }
    __syncthreads();
    for (int u = t; u < 768; u += 256) {
        int w = u >> 3, c8 = (u & 7) * 8;
        __bf16 tmp[8];
#pragma unroll
        for (int i = 0; i < 8; ++i) tmp[i] = (__bf16)sT[w][c8 + i];
        *(uint4*)&X2[(((size_t)(b * 96 + h)) * 96 + w) * CH2 + g * 64 + c8] =
            *(const uint4*)tmp;
    }
}

// ---------------------------------------------------------------------------
// Weight prep
// ---------------------------------------------------------------------------
__global__ __launch_bounds__(256) void cvt_taps(const float* __restrict__ w,
                                                __bf16* __restrict__ out,
                                                int Cout, int Cin, int CoutPad) {
    int e = blockIdx.x * 256 + threadIdx.x;
    int tot = Cout * Cin * 9;
    if (e >= tot) return;
    int co = e / (Cin * 9);
    int r  = e - co * (Cin * 9);
    int ci = r / 9;
    int k  = r - ci * 9;
    out[((size_t)k * CoutPad + co) * Cin + ci] = (__bf16)w[e];
}

__global__ __launch_bounds__(256) void cvt_flat(const float* __restrict__ w,
                                                __bf16* __restrict__ out, int n) {
    int e = blockIdx.x * 256 + threadIdx.x;
    if (e < n) out[e] = (__bf16)w[e];
}

// DCN weights: dcn_w[o][g*64+c][ktap] -> wA[o*4032 + g*576 + ktap*64 + c] bf16
__global__ __launch_bounds__(256) void cvt_dcnA(const float* __restrict__ w,
                                                __bf16* __restrict__ out) {
    int e = blockIdx.x * 256 + threadIdx.x;
    if (e >= 256 * 4032) return;
    int co = e / 4032;
    int r  = e - co * 4032;
    int g  = r / 576;
    int r2 = r - g * 576;
    int tap = r2 >> 6;
    int c   = r2 & 63;
    out[e] = (__bf16)w[((size_t)co * 448 + g * 64 + c) * 9 + tap];
}

// ---------------------------------------------------------------------------
// MFMA conv3x3 (+bias,+relu) -> optional MFMA 1x1 (+bias).
// Software-pipelined: chunk k+1's staging loads issued before GEMM of chunk k.
// ---------------------------------------------------------------------------
template<int MPW, int MODE>
__global__ __launch_bounds__(256, 3) void conv3x3_mfma(
    const __bf16* __restrict__ X2,
    const __bf16* __restrict__ wT2,   // [(tap*CmidPad + co)*Cin + ci]
    const float* __restrict__ b1,
    const __bf16* __restrict__ w2b,   // [cf*256 + co]
    const float* __restrict__ b2,
    float* __restrict__ out,
    int Cin, int CmidPad, int Cf, int chanBase, int whMap)
{
    constexpr int SBYTES = (MODE == 2) ? 23520 : 50688;
    __shared__ __align__(16) char smem[SBYTES];
    __bf16 (*sX)[98][40] = (__bf16 (*)[98][40])smem;

    const int h    = blockIdx.x;
    const int img  = blockIdx.y;
    const int t    = threadIdx.x;
    const int wave = t >> 6;
    const int lane = t & 63;
    const int lq   = lane >> 4;
    const int lr   = lane & 15;
    const int mbase = wave * (MPW * 16);

    const int bImg = whMap ? (img & 3) : img;
    const int cb   = whMap ? ((img >> 2) * 64) : chanBase;
    const __bf16* Xrow = X2 + ((size_t)bImg * 96) * 96 * CH2;

    // ---- chunk-invariant staging geometry (5 jobs/thread, 1176 total) -----
    int soff[5];   // byte offset into Xrow (w/o kc term), -1 if OOB
    int sdst[5];   // byte offset into sX
#pragma unroll
    for (int i = 0; i < 5; ++i) {
        int u = t + i * 256;
        soff[i] = -1; sdst[i] = 0;
        if (u < 1176) {
            int pos = u >> 2, q = u & 3;
            int r = pos / 98, gw = pos - r * 98;
            int gh = h - 1 + r, gx = gw - 1;
            sdst[i] = ((r * 98 + gw) * 40 + q * 8) * 2;
            if (((unsigned)gh < 96u) && ((unsigned)gx < 96u))
                soff[i] = ((gh * 96 + gx) * CH2 + cb + q * 8) * 2;
        }
    }
    uint4 pv[5];
    auto issue = [&](int kc) {
#pragma unroll
        for (int i = 0; i < 5; ++i) {
            uint4 v = {0u, 0u, 0u, 0u};
            if (t + i * 256 < 1176 && soff[i] >= 0)
                v = *(const uint4*)((const char*)Xrow + soff[i] + kc * 64);
            pv[i] = v;
        }
    };
    auto commit = [&]() {
#pragma unroll
        for (int i = 0; i < 5; ++i)
            if (t + i * 256 < 1176)
                *(uint4*)(smem + sdst[i]) = pv[i];
    };

    f32x4 acc[MPW][6];
#pragma unroll
    for (int mi = 0; mi < MPW; ++mi)
#pragma unroll
        for (int ni = 0; ni < 6; ++ni)
            acc[mi][ni] = (f32x4){0.f, 0.f, 0.f, 0.f};

    const int KC = Cin >> 5;
    issue(0);
    commit();
    __syncthreads();

    for (int kc = 0; kc < KC; ++kc) {
        if (kc + 1 < KC) issue(kc + 1);   // loads in flight during GEMM

        const __bf16* wbase = wT2 + ((size_t)(mbase + lr)) * Cin + kc * 32 + lq * 8;
#pragma unroll
        for (int tap = 0; tap < 9; ++tap) {
            const int ky = tap / 3, kx = tap - ky * 3;
            bf16x8 aF[MPW];
#pragma unroll
            for (int mi = 0; mi < MPW; ++mi)
                aF[mi] = *(const bf16x8*)(wbase +
                          ((size_t)tap * CmidPad + mi * 16) * Cin);
#pragma unroll
            for (int ni = 0; ni < 6; ++ni) {
                bf16x8 bF = *(const bf16x8*)&sX[ky][ni * 16 + lr + kx][lq * 8];
#pragma unroll
                for (int mi = 0; mi < MPW; ++mi)
                    acc[mi][ni] = __builtin_amdgcn_mfma_f32_16x16x32_bf16(
                        aF[mi], bF, acc[mi][ni], 0, 0, 0);
            }
        }
        __syncthreads();                  // all waves done reading sX
        if (kc + 1 < KC) {
            commit();
            __syncthreads();
        }
    }

    if (MODE == 2) {
#pragma unroll
        for (int mi = 0; mi < MPW; ++mi)
#pragma unroll
            for (int ni = 0; ni < 6; ++ni) {
                int px = ni * 16 + lr;
#pragma unroll
                for (int r = 0; r < 4; ++r) {
                    int co = mbase + mi * 16 + lq * 4 + r;
                    if (co < Cf)
                        out[((size_t)(img * 189 + co)) * HWSZ + h * WW + px] =
                            acc[mi][ni][r] + b1[co];
                }
            }
        return;
    } else {
        // post-GEMM barrier already executed; safe to overlay
        __bf16 (*sH)[264] = (__bf16 (*)[264])smem;
#pragma unroll
        for (int mi = 0; mi < MPW; ++mi) {
            int co0 = mbase + mi * 16 + lq * 4;
            float bb0 = b1[co0], bb1 = b1[co0 + 1], bb2 = b1[co0 + 2], bb3 = b1[co0 + 3];
#pragma unroll
            for (int ni = 0; ni < 6; ++ni) {
                int px = ni * 16 + lr;
                bf16x4 hv;
                hv[0] = (__bf16)fmaxf(acc[mi][ni][0] + bb0, 0.f);
                hv[1] = (__bf16)fmaxf(acc[mi][ni][1] + bb1, 0.f);
                hv[2] = (__bf16)fmaxf(acc[mi][ni][2] + bb2, 0.f);
                hv[3] = (__bf16)fmaxf(acc[mi][ni][3] + bb3, 0.f);
                *(bf16x4*)&sH[px][co0] = hv;
            }
        }
        __syncthreads();

        const int MT2 = (Cf + 15) >> 4;
        for (int tt = wave; tt < MT2 * 6; tt += 4) {
            int ni = tt / MT2;
            int mt = tt - ni * MT2;
            int cf = mt * 16 + lr; if (cf > Cf - 1) cf = Cf - 1;
            const __bf16* wrow = w2b + (size_t)cf * 256 + lq * 8;
            f32x4 c = (f32x4){0.f, 0.f, 0.f, 0.f};
#pragma unroll
            for (int kc = 0; kc < 8; ++kc) {
                bf16x8 aF = *(const bf16x8*)(wrow + kc * 32);
                bf16x8 bF = *(const bf16x8*)&sH[ni * 16 + lr][kc * 32 + lq * 8];
                c = __builtin_amdgcn_mfma_f32_16x16x32_bf16(aF, bF, c, 0, 0, 0);
            }
            int px = ni * 16 + lr;
#pragma unroll
            for (int r = 0; r < 4; ++r) {
                int cfr = mt * 16 + lq * 4 + r;
                if (cfr < Cf) {
                    int och;
                    if (MODE == 1) {
                        och = (img & 3) * 14 + (img >> 2) * 2 + cfr;
                    } else {
                        och = img * Cf + cfr;
                    }
                    out[(size_t)och * HWSZ + h * WW + px] = c[r] + b2[cfr];
                }
            }
        }
    }
}

// ---------------------------------------------------------------------------
// DCNv2 via MFMA + bias + BN + ReLU + bz 1x1, fused & software-pipelined.
// Block = (b, h, 32-px tile), grid 1152. Once-per-block tap table in LDS
// (u16 base index + fp16 weight quad, validity & sigmoid(mask) folded in).
// Corner gather for chunk c+1 issued before GEMM of chunk c.
// ---------------------------------------------------------------------------
#define DNP 32
__global__ __launch_bounds__(256, 4) void dcn_bz_mfma(
    const __bf16* __restrict__ X2,
    const float* __restrict__ offmap,   // (B,189,H,W) fp32
    const __bf16* __restrict__ wA,      // [co][4032]
    const float* __restrict__ dcn_b,
    const float* __restrict__ bn_g, const float* __restrict__ bn_be,
    const float* __restrict__ bn_mn, const float* __restrict__ bn_vr,
    const __bf16* __restrict__ bzwb,    // [16][256]
    const float* __restrict__ bzb,
    float* __restrict__ out_bz)
{
    // LDS: sW4 [63][32] half4 (16128) | sIdx [63][32] u16 (4032) |
    //      sC [6][32][40] bf16 (15360)  -> 35520 B. sD [8][32][40] overlays base.
    __shared__ __align__(16) char smem[35520];
    half4v (*sW4)[DNP]          = (half4v (*)[DNP])smem;
    unsigned short (*sIdx)[DNP] = (unsigned short (*)[DNP])(smem + 16128);
    __bf16 (*sC)[DNP][40]       = (__bf16 (*)[DNP][40])(smem + 20160);
    __bf16 (*sD)[DNP][40]       = (__bf16 (*)[DNP][40])smem;

    const int b    = blockIdx.y;
    const int h    = blockIdx.x / 3;
    const int w0   = (blockIdx.x - h * 3) * DNP;
    const int t    = threadIdx.x;
    const int wave = t >> 6;
    const int lane = t & 63;
    const int lq   = lane >> 4;
    const int lr   = lane & 15;
    const int mbase = wave * 64;

    const float* offp = offmap + (size_t)b * 189 * HWSZ;
    const __bf16* Xb  = X2 + ((size_t)b * 96) * 96 * CH2;

    // ---- tap table: 63 gk x 32 px ----------------------------------------
    for (int e = t; e < 63 * DNP; e += 256) {
        int gk = e / DNP;
        int px = e - gk * DNP;
        int tap = gk % 9;
        int pix = h * WW + w0 + px;
        float oy = offp[(size_t)gk * HWSZ + pix];
        float ox = offp[(size_t)(63 + gk) * HWSZ + pix];
        float mv = offp[(size_t)(126 + gk) * HWSZ + pix];
        float m  = 1.f / (1.f + expf(-mv));
        int ky = tap / 3, kx = tap - ky * 3;
        float sy = (float)(h - 1 + ky) + oy;
        float sx = (float)(w0 + px - 1 + kx) + ox;
        float fy = floorf(sy), fx = floorf(sx);
        float wy = sy - fy,    wx = sx - fx;
        int y0 = (int)fy, x0 = (int)fx;
        int by = min(max(y0, 0), 94);
        int bx = min(max(x0, 0), 94);
        float wy0 = (y0 == by ? 1.f - wy : 0.f) + (y0 + 1 == by ? wy : 0.f);
        float wy1 = (y0 == by + 1 ? 1.f - wy : 0.f) + (y0 + 1 == by + 1 ? wy : 0.f);
        float wx0 = (x0 == bx ? 1.f - wx : 0.f) + (x0 + 1 == bx ? wx : 0.f);
        float wx1 = (x0 == bx + 1 ? 1.f - wx : 0.f) + (x0 + 1 == bx + 1 ? wx : 0.f);
        half4v w4;
        w4[0] = (_Float16)(m * wy0 * wx0);
        w4[1] = (_Float16)(m * wy0 * wx1);
        w4[2] = (_Float16)(m * wy1 * wx0);
        w4[3] = (_Float16)(m * wy1 * wx1);
        sW4[gk][px] = w4;
        sIdx[gk][px] = (unsigned short)(by * WW + bx);
    }
    __syncthreads();

    // ---- gather state (thread-fixed geometry) -----------------------------
    const bool act = t < 192;                 // 2 halves x 3 taps x 32 px
    const int jhalf = t / 96;
    const int jp    = t - jhalf * 96;
    const int jtl   = jp / DNP;
    const int jpx   = jp - jtl * DNP;
    const int kcDst = jtl * 2 + jhalf;

    bf16x8 pc[8];          // prefetched corners (c8 = 0,1) x 4
    half4v w4r = (half4v){0, 0, 0, 0};
    const __bf16* pl = Xb;

    auto issue = [&](int g, int c3) {
        if (act) {
            int gk = g * 9 + c3 * 3 + jtl;
            w4r = sW4[gk][jpx];
            int idx = sIdx[gk][jpx];
            pl = Xb + (size_t)idx * CH2 + g * 64 + jhalf * 32;
#pragma unroll
            for (int c8 = 0; c8 < 2; ++c8) {
                pc[c8 * 4 + 0] = *(const bf16x8*)(pl + c8 * 8);
                pc[c8 * 4 + 1] = *(const bf16x8*)(pl + CH2 + c8 * 8);
                pc[c8 * 4 + 2] = *(const bf16x8*)(pl + 96 * CH2 + c8 * 8);
                pc[c8 * 4 + 3] = *(const bf16x8*)(pl + 97 * CH2 + c8 * 8);
            }
        }
    };
    auto fma_write = [&]() {
        if (act) {
            float w00 = (float)w4r[0], w01 = (float)w4r[1];
            float w10 = (float)w4r[2], w11 = (float)w4r[3];
#pragma unroll
            for (int c8 = 0; c8 < 4; ++c8) {
                bf16x8 c00, c01, c10, c11;
                if (c8 < 2) {
                    c00 = pc[c8 * 4 + 0]; c01 = pc[c8 * 4 + 1];
                    c10 = pc[c8 * 4 + 2]; c11 = pc[c8 * 4 + 3];
                } else {      // same 64B line as prefetched half -> L1 hit
                    c00 = *(const bf16x8*)(pl + c8 * 8);
                    c01 = *(const bf16x8*)(pl + CH2 + c8 * 8);
                    c10 = *(const bf16x8*)(pl + 96 * CH2 + c8 * 8);
                    c11 = *(const bf16x8*)(pl + 97 * CH2 + c8 * 8);
                }
                __bf16 tmp[8];
#pragma unroll
                for (int i = 0; i < 8; ++i) {
                    float v = w00 * (float)c00[i] + w01 * (float)c01[i] +
                              w10 * (float)c10[i] + w11 * (float)c11[i];
                    tmp[i] = (__bf16)v;
                }
                *(uint4*)&sC[kcDst][jpx][c8 * 8] = *(const uint4*)tmp;
            }
        }
    };

    f32x4 acc[4][2];
#pragma unroll
    for (int mi = 0; mi < 4; ++mi)
#pragma unroll
        for (int ni = 0; ni < 2; ++ni)
            acc[mi][ni] = (f32x4){0.f, 0.f, 0.f, 0.f};

    issue(0, 0);
    for (int ci = 0; ci < 21; ++ci) {
        int g = ci / 3, c3 = ci - g * 3;
        __syncthreads();                 // previous GEMM done reading sC
        fma_write();
        __syncthreads();                 // sC ready
        if (ci < 20) { int cn = ci + 1; issue(cn / 3, cn - (cn / 3) * 3); }

        const __bf16* wbase = wA + (size_t)(mbase + lr) * 4032 +
                              (g * 18 + c3 * 6) * 32 + lq * 8;
#pragma unroll
        for (int kc = 0; kc < 6; ++kc) {
            bf16x8 aF[4];
#pragma unroll
            for (int mi = 0; mi < 4; ++mi)
                aF[mi] = *(const bf16x8*)(wbase + (size_t)mi * 16 * 4032 + kc * 32);
#pragma unroll
            for (int ni = 0; ni < 2; ++ni) {
                bf16x8 bF = *(const bf16x8*)&sC[kc][ni * 16 + lr][lq * 8];
#pragma unroll
                for (int mi = 0; mi < 4; ++mi)
                    acc[mi][ni] = __builtin_amdgcn_mfma_f32_16x16x32_bf16(
                        aF[mi], bF, acc[mi][ni], 0, 0, 0);
            }
        }
    }

    // ---- epilogue: bias + BN + relu -> channels-last bf16 LDS -------------
    __syncthreads();
#pragma unroll
    for (int mi = 0; mi < 4; ++mi) {
        int co0 = mbase + mi * 16 + lq * 4;
        float sc[4], sh[4];
#pragma unroll
        for (int r = 0; r < 4; ++r) {
            float s = bn_g[co0 + r] * rsqrtf(bn_vr[co0 + r] + 1e-5f);
            sc[r] = s;
            sh[r] = (dcn_b[co0 + r] - bn_mn[co0 + r]) * s + bn_be[co0 + r];
        }
#pragma unroll
        for (int ni = 0; ni < 2; ++ni) {
            int px = ni * 16 + lr;
            bf16x4 hv;
#pragma unroll
            for (int r = 0; r < 4; ++r)
                hv[r] = (__bf16)fmaxf(acc[mi][ni][r] * sc[r] + sh[r], 0.f);
            *(bf16x4*)&sD[co0 >> 5][px][co0 & 31] = hv;
        }
    }
    __syncthreads();

    // ---- bz 1x1: M=16, K=256, N=32 (2 n-tiles on waves 0..1) --------------
    if (wave < 2) {
        int ni = wave;
        const __bf16* wrow = bzwb + (size_t)lr * 256 + lq * 8;
        f32x4 c = (f32x4){0.f, 0.f, 0.f, 0.f};
#pragma unroll
        for (int kc = 0; kc < 8; ++kc) {
            bf16x8 aF = *(const bf16x8*)(wrow + kc * 32);
            bf16x8 bF = *(const bf16x8*)&sD[kc][ni * 16 + lr][lq * 8];
            c = __builtin_amdgcn_mfma_f32_16x16x32_bf16(aF, bF, c, 0, 0, 0);
        }
        int px = ni * 16 + lr;
#pragma unroll
        for (int r = 0; r < 4; ++r) {
            int cf = lq * 4 + r;
            out_bz[((size_t)(b * 16 + cf)) * HWSZ + h * WW + w0 + px] = c[r] + bzb[cf];
        }
    }
}

// ---------------------------------------------------------------------------
// Launch
// ---------------------------------------------------------------------------
extern "C" void kernel_launch(void* const* d_in, const int* in_sizes, int n_in,
                              void* d_out, int out_size, void* d_ws, size_t ws_size,
                              hipStream_t stream) {
    const float* feat   = (const float*)d_in[0];
    const float* hm_w1  = (const float*)d_in[1];
    const float* hm_b1  = (const float*)d_in[2];
    const float* hm_w2  = (const float*)d_in[3];
    const float* hm_b2  = (const float*)d_in[4];
    const float* wh_w1  = (const float*)d_in[5];
    const float* wh_b1  = (const float*)d_in[6];
    const float* wh_w2  = (const float*)d_in[7];
    const float* wh_b2  = (const float*)d_in[8];
    const float* id_w1  = (const float*)d_in[9];
    const float* id_b1  = (const float*)d_in[10];
    const float* id_w2  = (const float*)d_in[11];
    const float* id_b2  = (const float*)d_in[12];
    const float* off_w  = (const float*)d_in[13];
    const float* off_b  = (const float*)d_in[14];
    const float* dcn_w  = (const float*)d_in[15];
    const float* dcn_b  = (const float*)d_in[16];
    const float* bn_g   = (const float*)d_in[17];
    const float* bn_be  = (const float*)d_in[18];
    const float* bn_mn  = (const float*)d_in[19];
    const float* bn_vr  = (const float*)d_in[20];
    const float* bz_w   = (const float*)d_in[21];
    const float* bz_b   = (const float*)d_in[22];

    // Workspace layout
    float* ws      = (float*)d_ws;
    float* off_out = ws;                        // 6,967,296 f (27.9 MB)
    __bf16* X2     = (__bf16*)(off_out + 6967296); // 16,515,072 bf16
    __bf16* bfw    = X2 + 16515072;
    __bf16* wh_wT2 = bfw;                       // 147,456
    __bf16* hm_wT2 = wh_wT2 + 147456;           // 147,456
    __bf16* id_wT2 = hm_wT2 + 147456;           // 1,032,192
    __bf16* off_wT2= id_wT2 + 1032192;          // 774,144
    __bf16* wh_w2b = off_wT2 + 774144;          //     512
    __bf16* hm_w2b = wh_w2b + 512;              //    6144
    __bf16* id_w2b = hm_w2b + 6144;             //   32768
    __bf16* dcn_wA = id_w2b + 32768;            // 1,032,192
    __bf16* bz_wb  = dcn_wA + 1032192;          //    4096

    // Output layout (floats, concatenated): hm, bz, idout, owh
    float* out_hm = (float*)d_out;              // (4,24,96,96)
    float* out_bz = out_hm + 884736;            // (4,16,96,96)
    float* out_id = out_bz + 589824;            // (4,128,96,96)
    float* out_wh = out_id + 4718592;           // (4,14,96,96)

    // 1) data + weight prep
    cvt_feat<<<dim3(96, 28), 256, 0, stream>>>(feat, X2);
    cvt_taps<<<(147456 + 255) / 256, 256, 0, stream>>>(wh_w1, wh_wT2, 256, 64, 256);
    cvt_taps<<<(147456 + 255) / 256, 256, 0, stream>>>(hm_w1, hm_wT2, 256, 64, 256);
    cvt_taps<<<(1032192 + 255) / 256, 256, 0, stream>>>(id_w1, id_wT2, 256, 448, 256);
    cvt_taps<<<(762048 + 255) / 256, 256, 0, stream>>>(off_w, off_wT2, 189, 448, 192);
    cvt_flat<<<(512 + 255) / 256, 256, 0, stream>>>(wh_w2, wh_w2b, 512);
    cvt_flat<<<(6144 + 255) / 256, 256, 0, stream>>>(hm_w2, hm_w2b, 6144);
    cvt_flat<<<(32768 + 255) / 256, 256, 0, stream>>>(id_w2, id_w2b, 32768);
    cvt_flat<<<(4096 + 255) / 256, 256, 0, stream>>>(bz_w, bz_wb, 4096);
    cvt_dcnA<<<(1032192 + 255) / 256, 256, 0, stream>>>(dcn_w, dcn_wA);

    // 2) MFMA conv branches (staging from channels-last X2, pipelined)
    conv3x3_mfma<4, 1><<<dim3(96, 28), 256, 0, stream>>>(
        X2, wh_wT2, wh_b1, wh_w2b, wh_b2, out_wh, 64, 256, 2, 0, 1);
    conv3x3_mfma<4, 0><<<dim3(96, 4), 256, 0, stream>>>(
        X2, hm_wT2, hm_b1, hm_w2b, hm_b2, out_hm, 64, 256, 24, 192, 0);
    conv3x3_mfma<4, 0><<<dim3(96, 4), 256, 0, stream>>>(
        X2, id_wT2, id_b1, id_w2b, id_b2, out_id, 448, 256, 128, 0, 0);
    conv3x3_mfma<3, 2><<<dim3(96, 4), 256, 0, stream>>>(
        X2, off_wT2, off_b, nullptr, nullptr, off_out, 448, 192, 189, 0, 0);

    // 3) DCN via MFMA + BN + ReLU + bz (consumes off_out + X2)
    dcn_bz_mfma<<<dim3(288, 4), 256, 0, stream>>>(
        X2, off_out, dcn_wA, dcn_b, bn_g, bn_be, bn_mn, bn_vr,
        bz_wb, bz_b, out_bz);
}

// Round 6
// 922.700 us; speedup vs baseline: 1.5565x; 1.5565x over previous
//
#include <hip/hip_runtime.h>
#include <hip/hip_bf16.h>
#include <math.h>

// Problem constants
#define KF   7      // frames / groups
#define BB_  4      // batch
#define CC_  64     // channels per frame
#define HH   96
#define WW   96
#define HWSZ 9216   // 96*96
#define HEAD 256
#define CH2  448    // channels-last width of X2

typedef __bf16 bf16x8 __attribute__((ext_vector_type(8)));
typedef __bf16 bf16x4 __attribute__((ext_vector_type(4)));
typedef float  f32x4  __attribute__((ext_vector_type(4)));
typedef _Float16 half4v __attribute__((ext_vector_type(4)));

// ---------------------------------------------------------------------------
// features (K,B,C,H,W) fp32 -> X2[b][h][w][g*64+c] bf16 (channels-last)
// ---------------------------------------------------------------------------
__global__ __launch_bounds__(256) void cvt_feat(const float* __restrict__ feat,
                                                __bf16* __restrict__ X2) {
    __shared__ float sT[96][65];
    const int h = blockIdx.x;
    const int n = blockIdx.y;          // g*4+b
    const int g = n >> 2, b = n & 3;
    const int t = threadIdx.x;
    const float* src = feat + (size_t)n * 64 * HWSZ + h * WW;
    for (int e = t; e < 6144; e += 256) {
        int c = e / 96, w = e - c * 96;
        sT[w][c] = src[(size_t)c * HWSZ + w];
    }
    __syncthreads();
    for (int u = t; u < 768; u += 256) {
        int w = u >> 3, c8 = (u & 7) * 8;
        __bf16 tmp[8];
#pragma unroll
        for (int i = 0; i < 8; ++i) tmp[i] = (__bf16)sT[w][c8 + i];
        *(uint4*)&X2[(((size_t)(b * 96 + h)) * 96 + w) * CH2 + g * 64 + c8] =
            *(const uint4*)tmp;
    }
}

// ---------------------------------------------------------------------------
// Weight prep
// ---------------------------------------------------------------------------
__global__ __launch_bounds__(256) void cvt_taps(const float* __restrict__ w,
                                                __bf16* __restrict__ out,
                                                int Cout, int Cin, int CoutPad) {
    int e = blockIdx.x * 256 + threadIdx.x;
    int tot = Cout * Cin * 9;
    if (e >= tot) return;
    int co = e / (Cin * 9);
    int r  = e - co * (Cin * 9);
    int ci = r / 9;
    int k  = r - ci * 9;
    out[((size_t)k * CoutPad + co) * Cin + ci] = (__bf16)w[e];
}

__global__ __launch_bounds__(256) void cvt_flat(const float* __restrict__ w,
                                                __bf16* __restrict__ out, int n) {
    int e = blockIdx.x * 256 + threadIdx.x;
    if (e < n) out[e] = (__bf16)w[e];
}

// DCN weights: dcn_w[o][g*64+c][ktap] -> wA[o*4032 + g*576 + ktap*64 + c] bf16
__global__ __launch_bounds__(256) void cvt_dcnA(const float* __restrict__ w,
                                                __bf16* __restrict__ out) {
    int e = blockIdx.x * 256 + threadIdx.x;
    if (e >= 256 * 4032) return;
    int co = e / 4032;
    int r  = e - co * 4032;
    int g  = r / 576;
    int r2 = r - g * 576;
    int tap = r2 >> 6;
    int c   = r2 & 63;
    out[e] = (__bf16)w[((size_t)co * 448 + g * 64 + c) * 9 + tap];
}

// ---------------------------------------------------------------------------
// Tap table prep: off_out (B,189,HW) fp32 -> per (b,gk,pix):
//   idxT u16 clamped base index, wTab half4 bilinear weights
//   (validity + sigmoid(mask) folded in).
// ---------------------------------------------------------------------------
__global__ __launch_bounds__(256) void tap_prep(const float* __restrict__ off_out,
                                                unsigned short* __restrict__ idxT,
                                                half4v* __restrict__ wTab) {
    int e = blockIdx.x * 256 + threadIdx.x;
    if (e >= BB_ * 63 * HWSZ) return;
    int b   = e / (63 * HWSZ);
    int r   = e - b * (63 * HWSZ);
    int gk  = r / HWSZ;
    int pix = r - gk * HWSZ;
    int h = pix / WW, w = pix - h * WW;
    int tap = gk % 9;
    const float* offp = off_out + (size_t)b * 189 * HWSZ;
    float oy = offp[(size_t)gk * HWSZ + pix];
    float ox = offp[(size_t)(63 + gk) * HWSZ + pix];
    float mv = offp[(size_t)(126 + gk) * HWSZ + pix];
    float m  = 1.f / (1.f + expf(-mv));
    int ky = tap / 3, kx = tap - ky * 3;
    float sy = (float)(h - 1 + ky) + oy;
    float sx = (float)(w - 1 + kx) + ox;
    float fy = floorf(sy), fx = floorf(sx);
    float wy = sy - fy,    wx = sx - fx;
    int y0 = (int)fy, x0 = (int)fx;
    int by = min(max(y0, 0), 94);
    int bx = min(max(x0, 0), 94);
    float wy0 = (y0 == by ? 1.f - wy : 0.f) + (y0 + 1 == by ? wy : 0.f);
    float wy1 = (y0 == by + 1 ? 1.f - wy : 0.f) + (y0 + 1 == by + 1 ? wy : 0.f);
    float wx0 = (x0 == bx ? 1.f - wx : 0.f) + (x0 + 1 == bx ? wx : 0.f);
    float wx1 = (x0 == bx + 1 ? 1.f - wx : 0.f) + (x0 + 1 == bx + 1 ? wx : 0.f);
    half4v w4;
    w4[0] = (_Float16)(m * wy0 * wx0);
    w4[1] = (_Float16)(m * wy0 * wx1);
    w4[2] = (_Float16)(m * wy1 * wx0);
    w4[3] = (_Float16)(m * wy1 * wx1);
    idxT[e] = (unsigned short)(by * WW + bx);
    wTab[e] = w4;
}

// ---------------------------------------------------------------------------
// MFMA conv3x3 (+bias,+relu) -> optional MFMA 1x1 (+bias).  (round-4 version)
// ---------------------------------------------------------------------------
template<int MPW, int MODE>
__global__ __launch_bounds__(256) void conv3x3_mfma(
    const __bf16* __restrict__ X2,
    const __bf16* __restrict__ wT2,   // [(tap*CmidPad + co)*Cin + ci]
    const float* __restrict__ b1,
    const __bf16* __restrict__ w2b,   // [cf*256 + co]
    const float* __restrict__ b2,
    float* __restrict__ out,
    int Cin, int CmidPad, int Cf, int chanBase, int whMap)
{
    constexpr int SBYTES = (MODE == 2) ? 23520 : 50688;
    __shared__ __align__(16) char smem[SBYTES];
    __bf16 (*sX)[98][40] = (__bf16 (*)[98][40])smem;

    const int h    = blockIdx.x;
    const int img  = blockIdx.y;
    const int t    = threadIdx.x;
    const int wave = t >> 6;
    const int lane = t & 63;
    const int lq   = lane >> 4;
    const int lr   = lane & 15;
    const int mbase = wave * (MPW * 16);

    const int bImg = whMap ? (img & 3) : img;
    const int cb   = whMap ? ((img >> 2) * 64) : chanBase;
    const __bf16* Xrow = X2 + ((size_t)bImg * 96) * 96 * CH2;

    f32x4 acc[MPW][6];
#pragma unroll
    for (int mi = 0; mi < MPW; ++mi)
#pragma unroll
        for (int ni = 0; ni < 6; ++ni)
            acc[mi][ni] = (f32x4){0.f, 0.f, 0.f, 0.f};

    const int KC = Cin >> 5;
    for (int kc = 0; kc < KC; ++kc) {
        __syncthreads();
        // ---- stage: 294 positions x 32ch (64 B each) via uint4 ------------
        for (int u = t; u < 1176; u += 256) {
            int pos = u >> 2;
            int q   = u & 3;
            int r   = pos / 98;
            int gw  = pos - r * 98;
            int gh  = h - 1 + r;
            int gx  = gw - 1;
            uint4 v = {0u, 0u, 0u, 0u};
            if (((unsigned)gh < 96u) && ((unsigned)gx < 96u))
                v = *(const uint4*)&Xrow[((size_t)gh * 96 + gx) * CH2 +
                                         cb + kc * 32 + q * 8];
            *(uint4*)&sX[r][gw][q * 8] = v;
        }
        __syncthreads();

        const __bf16* wbase = wT2 + ((size_t)(mbase + lr)) * Cin + kc * 32 + lq * 8;
#pragma unroll
        for (int tap = 0; tap < 9; ++tap) {
            const int ky = tap / 3, kx = tap - ky * 3;
            bf16x8 aF[MPW];
#pragma unroll
            for (int mi = 0; mi < MPW; ++mi)
                aF[mi] = *(const bf16x8*)(wbase +
                          ((size_t)tap * CmidPad + mi * 16) * Cin);
#pragma unroll
            for (int ni = 0; ni < 6; ++ni) {
                bf16x8 bF = *(const bf16x8*)&sX[ky][ni * 16 + lr + kx][lq * 8];
#pragma unroll
                for (int mi = 0; mi < MPW; ++mi)
                    acc[mi][ni] = __builtin_amdgcn_mfma_f32_16x16x32_bf16(
                        aF[mi], bF, acc[mi][ni], 0, 0, 0);
            }
        }
    }

    if (MODE == 2) {
#pragma unroll
        for (int mi = 0; mi < MPW; ++mi)
#pragma unroll
            for (int ni = 0; ni < 6; ++ni) {
                int px = ni * 16 + lr;
#pragma unroll
                for (int r = 0; r < 4; ++r) {
                    int co = mbase + mi * 16 + lq * 4 + r;
                    if (co < Cf)
                        out[((size_t)(img * 189 + co)) * HWSZ + h * WW + px] =
                            acc[mi][ni][r] + b1[co];
                }
            }
        return;
    } else {
        __syncthreads();
        __bf16 (*sH)[264] = (__bf16 (*)[264])smem;
#pragma unroll
        for (int mi = 0; mi < MPW; ++mi) {
            int co0 = mbase + mi * 16 + lq * 4;
            float bb0 = b1[co0], bb1 = b1[co0 + 1], bb2 = b1[co0 + 2], bb3 = b1[co0 + 3];
#pragma unroll
            for (int ni = 0; ni < 6; ++ni) {
                int px = ni * 16 + lr;
                bf16x4 hv;
                hv[0] = (__bf16)fmaxf(acc[mi][ni][0] + bb0, 0.f);
                hv[1] = (__bf16)fmaxf(acc[mi][ni][1] + bb1, 0.f);
                hv[2] = (__bf16)fmaxf(acc[mi][ni][2] + bb2, 0.f);
                hv[3] = (__bf16)fmaxf(acc[mi][ni][3] + bb3, 0.f);
                *(bf16x4*)&sH[px][co0] = hv;
            }
        }
        __syncthreads();

        const int MT2 = (Cf + 15) >> 4;
        for (int tt = wave; tt < MT2 * 6; tt += 4) {
            int ni = tt / MT2;
            int mt = tt - ni * MT2;
            int cf = mt * 16 + lr; if (cf > Cf - 1) cf = Cf - 1;
            const __bf16* wrow = w2b + (size_t)cf * 256 + lq * 8;
            f32x4 c = (f32x4){0.f, 0.f, 0.f, 0.f};
#pragma unroll
            for (int kc = 0; kc < 8; ++kc) {
                bf16x8 aF = *(const bf16x8*)(wrow + kc * 32);
                bf16x8 bF = *(const bf16x8*)&sH[ni * 16 + lr][kc * 32 + lq * 8];
                c = __builtin_amdgcn_mfma_f32_16x16x32_bf16(aF, bF, c, 0, 0, 0);
            }
            int px = ni * 16 + lr;
#pragma unroll
            for (int r = 0; r < 4; ++r) {
                int cfr = mt * 16 + lq * 4 + r;
                if (cfr < Cf) {
                    int och;
                    if (MODE == 1) {
                        och = (img & 3) * 14 + (img >> 2) * 2 + cfr;
                    } else {
                        och = img * Cf + cfr;
                    }
                    out[(size_t)och * HWSZ + h * WW + px] = c[r] + b2[cfr];
                }
            }
        }
    }
}

// ---------------------------------------------------------------------------
// DCNv2 via MFMA + bias + BN + ReLU + bz 1x1, fused.  (round-4 structure,
// gather driven by precomputed tap table; next chunk's table entries
// prefetched into registers before each GEMM.)
// ---------------------------------------------------------------------------
#define DNP 48
__global__ __launch_bounds__(256) void dcn_bz_mfma(
    const __bf16* __restrict__ X2,
    const unsigned short* __restrict__ idxT,  // (B,63,HW)
    const half4v* __restrict__ wTab,          // (B,63,HW)
    const __bf16* __restrict__ wA,            // [co][4032]
    const float* __restrict__ dcn_b,
    const float* __restrict__ bn_g, const float* __restrict__ bn_be,
    const float* __restrict__ bn_mn, const float* __restrict__ bn_vr,
    const __bf16* __restrict__ bzwb,          // [16][256]
    const float* __restrict__ bzb,
    float* __restrict__ out_bz)
{
    __shared__ __align__(16) char smem[30720];
    __bf16 (*sC)[DNP][40] = (__bf16 (*)[DNP][40])smem;   // [6][48][40] staging
    __bf16 (*sD)[DNP][40] = (__bf16 (*)[DNP][40])smem;   // [8][48][40] epilogue

    const int b    = blockIdx.y;
    const int h    = blockIdx.x >> 1;
    const int w0   = (blockIdx.x & 1) * DNP;
    const int t    = threadIdx.x;
    const int wave = t >> 6;
    const int lane = t & 63;
    const int lq   = lane >> 4;
    const int lr   = lane & 15;
    const int mbase = wave * 64;

    const __bf16* Xb = X2 + ((size_t)b * 96) * 96 * CH2;
    const int pix0 = h * WW + w0;
    const int tb   = b * 63;

    // per-thread job geometry (up to 2 jobs of 288)
    bool jact[2]; int jhalf[2], jtl[2], jpx[2];
#pragma unroll
    for (int i = 0; i < 2; ++i) {
        int u = t + i * 256;
        jact[i] = u < 288;
        int half = u / 144;  int p = u - half * 144;
        int tl = p / DNP;    int px = p - tl * DNP;
        jhalf[i] = half; jtl[i] = tl; jpx[i] = px;
    }

    unsigned short nIdx[2] = {0, 0};
    half4v nW4[2] = {(half4v){0,0,0,0}, (half4v){0,0,0,0}};
    auto tload = [&](int ci) {
        int g = ci / 3, c3 = ci - g * 3;
#pragma unroll
        for (int i = 0; i < 2; ++i)
            if (jact[i]) {
                int ti = (tb + g * 9 + c3 * 3 + jtl[i]) * HWSZ + pix0 + jpx[i];
                nIdx[i] = idxT[ti];
                nW4[i]  = wTab[ti];
            }
    };

    f32x4 acc[4][3];
#pragma unroll
    for (int mi = 0; mi < 4; ++mi)
#pragma unroll
        for (int ni = 0; ni < 3; ++ni)
            acc[mi][ni] = (f32x4){0.f, 0.f, 0.f, 0.f};

    tload(0);
    for (int ci = 0; ci < 21; ++ci) {
        int g = ci / 3, c3 = ci - g * 3;
        __syncthreads();     // previous GEMM done reading sC
        // ---- gather using table entries -----------------------------------
#pragma unroll
        for (int i = 0; i < 2; ++i)
            if (jact[i]) {
                float w00 = (float)nW4[i][0], w01 = (float)nW4[i][1];
                float w10 = (float)nW4[i][2], w11 = (float)nW4[i][3];
                const __bf16* pl = Xb + (size_t)nIdx[i] * CH2 +
                                   g * 64 + jhalf[i] * 32;
                int kcDst = jtl[i] * 2 + jhalf[i];
#pragma unroll
                for (int c8 = 0; c8 < 4; ++c8) {
                    bf16x8 c00 = *(const bf16x8*)(pl + c8 * 8);
                    bf16x8 c01 = *(const bf16x8*)(pl + CH2 + c8 * 8);
                    bf16x8 c10 = *(const bf16x8*)(pl + 96 * CH2 + c8 * 8);
                    bf16x8 c11 = *(const bf16x8*)(pl + 97 * CH2 + c8 * 8);
                    __bf16 tmp[8];
#pragma unroll
                    for (int k = 0; k < 8; ++k) {
                        float v = w00 * (float)c00[k] + w01 * (float)c01[k] +
                                  w10 * (float)c10[k] + w11 * (float)c11[k];
                        tmp[k] = (__bf16)v;
                    }
                    *(uint4*)&sC[kcDst][jpx[i]][c8 * 8] = *(const uint4*)tmp;
                }
            }
        __syncthreads();
        if (ci < 20) tload(ci + 1);   // table loads in flight during GEMM

        // ---- GEMM over this K=192 chunk (6 sub-chunks of 32) --------------
        const __bf16* wbase = wA + (size_t)(mbase + lr) * 4032 +
                              (g * 18 + c3 * 6) * 32 + lq * 8;
#pragma unroll
        for (int kc = 0; kc < 6; ++kc) {
            bf16x8 aF[4];
#pragma unroll
            for (int mi = 0; mi < 4; ++mi)
                aF[mi] = *(const bf16x8*)(wbase + (size_t)mi * 16 * 4032 + kc * 32);
#pragma unroll
            for (int ni = 0; ni < 3; ++ni) {
                bf16x8 bF = *(const bf16x8*)&sC[kc][ni * 16 + lr][lq * 8];
#pragma unroll
                for (int mi = 0; mi < 4; ++mi)
                    acc[mi][ni] = __builtin_amdgcn_mfma_f32_16x16x32_bf16(
                        aF[mi], bF, acc[mi][ni], 0, 0, 0);
            }
        }
    }

    // ---- epilogue: bias + BN + relu -> channels-last bf16 LDS -------------
    __syncthreads();
#pragma unroll
    for (int mi = 0; mi < 4; ++mi) {
        int co0 = mbase + mi * 16 + lq * 4;
        float sc[4], sh[4];
#pragma unroll
        for (int r = 0; r < 4; ++r) {
            float s = bn_g[co0 + r] * rsqrtf(bn_vr[co0 + r] + 1e-5f);
            sc[r] = s;
            sh[r] = (dcn_b[co0 + r] - bn_mn[co0 + r]) * s + bn_be[co0 + r];
        }
#pragma unroll
        for (int ni = 0; ni < 3; ++ni) {
            int px = ni * 16 + lr;
            bf16x4 hv;
#pragma unroll
            for (int r = 0; r < 4; ++r)
                hv[r] = (__bf16)fmaxf(acc[mi][ni][r] * sc[r] + sh[r], 0.f);
            *(bf16x4*)&sD[co0 >> 5][px][co0 & 31] = hv;
        }
    }
    __syncthreads();

    // ---- bz 1x1: M=16, K=256, N=48 (3 n-tiles on waves 0..2) --------------
    if (wave < 3) {
        int ni = wave;
        const __bf16* wrow = bzwb + (size_t)lr * 256 + lq * 8;
        f32x4 c = (f32x4){0.f, 0.f, 0.f, 0.f};
#pragma unroll
        for (int kc = 0; kc < 8; ++kc) {
            bf16x8 aF = *(const bf16x8*)(wrow + kc * 32);
            bf16x8 bF = *(const bf16x8*)&sD[kc][ni * 16 + lr][lq * 8];
            c = __builtin_amdgcn_mfma_f32_16x16x32_bf16(aF, bF, c, 0, 0, 0);
        }
        int px = ni * 16 + lr;
#pragma unroll
        for (int r = 0; r < 4; ++r) {
            int cf = lq * 4 + r;
            out_bz[((size_t)(b * 16 + cf)) * HWSZ + h * WW + w0 + px] = c[r] + bzb[cf];
        }
    }
}

// ---------------------------------------------------------------------------
// Launch
// ---------------------------------------------------------------------------
extern "C" void kernel_launch(void* const* d_in, const int* in_sizes, int n_in,
                              void* d_out, int out_size, void* d_ws, size_t ws_size,
                              hipStream_t stream) {
    const float* feat   = (const float*)d_in[0];
    const float* hm_w1  = (const float*)d_in[1];
    const float* hm_b1  = (const float*)d_in[2];
    const float* hm_w2  = (const float*)d_in[3];
    const float* hm_b2  = (const float*)d_in[4];
    const float* wh_w1  = (const float*)d_in[5];
    const float* wh_b1  = (const float*)d_in[6];
    const float* wh_w2  = (const float*)d_in[7];
    const float* wh_b2  = (const float*)d_in[8];
    const float* id_w1  = (const float*)d_in[9];
    const float* id_b1  = (const float*)d_in[10];
    const float* id_w2  = (const float*)d_in[11];
    const float* id_b2  = (const float*)d_in[12];
    const float* off_w  = (const float*)d_in[13];
    const float* off_b  = (const float*)d_in[14];
    const float* dcn_w  = (const float*)d_in[15];
    const float* dcn_b  = (const float*)d_in[16];
    const float* bn_g   = (const float*)d_in[17];
    const float* bn_be  = (const float*)d_in[18];
    const float* bn_mn  = (const float*)d_in[19];
    const float* bn_vr  = (const float*)d_in[20];
    const float* bz_w   = (const float*)d_in[21];
    const float* bz_b   = (const float*)d_in[22];

    // Workspace layout
    float* ws      = (float*)d_ws;
    float* off_out = ws;                        // 6,967,296 f (27.9 MB)
    __bf16* X2     = (__bf16*)(off_out + 6967296); // 16,515,072 bf16 (33 MB)
    __bf16* bfw    = X2 + 16515072;
    __bf16* wh_wT2 = bfw;                       // 147,456
    __bf16* hm_wT2 = wh_wT2 + 147456;           // 147,456
    __bf16* id_wT2 = hm_wT2 + 147456;           // 1,032,192
    __bf16* off_wT2= id_wT2 + 1032192;          // 774,144
    __bf16* wh_w2b = off_wT2 + 774144;          //     512
    __bf16* hm_w2b = wh_w2b + 512;              //    6144
    __bf16* id_w2b = hm_w2b + 6144;             //   32768
    __bf16* dcn_wA = id_w2b + 32768;            // 1,032,192
    __bf16* bz_wb  = dcn_wA + 1032192;          //    4096
    // tap table (byte offset here is 8-aligned)
    half4v* wTab   = (half4v*)(bz_wb + 4096);   // 2,322,432 * 8 B (18.6 MB)
    unsigned short* idxT = (unsigned short*)(wTab + 2322432); // 4.6 MB

    // Output layout (floats, concatenated): hm, bz, idout, owh
    float* out_hm = (float*)d_out;              // (4,24,96,96)
    float* out_bz = out_hm + 884736;            // (4,16,96,96)
    float* out_id = out_bz + 589824;            // (4,128,96,96)
    float* out_wh = out_id + 4718592;           // (4,14,96,96)

    // 1) data + weight prep
    cvt_feat<<<dim3(96, 28), 256, 0, stream>>>(feat, X2);
    cvt_taps<<<(147456 + 255) / 256, 256, 0, stream>>>(wh_w1, wh_wT2, 256, 64, 256);
    cvt_taps<<<(147456 + 255) / 256, 256, 0, stream>>>(hm_w1, hm_wT2, 256, 64, 256);
    cvt_taps<<<(1032192 + 255) / 256, 256, 0, stream>>>(id_w1, id_wT2, 256, 448, 256);
    cvt_taps<<<(762048 + 255) / 256, 256, 0, stream>>>(off_w, off_wT2, 189, 448, 192);
    cvt_flat<<<(512 + 255) / 256, 256, 0, stream>>>(wh_w2, wh_w2b, 512);
    cvt_flat<<<(6144 + 255) / 256, 256, 0, stream>>>(hm_w2, hm_w2b, 6144);
    cvt_flat<<<(32768 + 255) / 256, 256, 0, stream>>>(id_w2, id_w2b, 32768);
    cvt_flat<<<(4096 + 255) / 256, 256, 0, stream>>>(bz_w, bz_wb, 4096);
    cvt_dcnA<<<(1032192 + 255) / 256, 256, 0, stream>>>(dcn_w, dcn_wA);

    // 2) MFMA conv branches (round-4 staging)
    conv3x3_mfma<4, 1><<<dim3(96, 28), 256, 0, stream>>>(
        X2, wh_wT2, wh_b1, wh_w2b, wh_b2, out_wh, 64, 256, 2, 0, 1);
    conv3x3_mfma<4, 0><<<dim3(96, 4), 256, 0, stream>>>(
        X2, hm_wT2, hm_b1, hm_w2b, hm_b2, out_hm, 64, 256, 24, 192, 0);
    conv3x3_mfma<4, 0><<<dim3(96, 4), 256, 0, stream>>>(
        X2, id_wT2, id_b1, id_w2b, id_b2, out_id, 448, 256, 128, 0, 0);
    conv3x3_mfma<3, 2><<<dim3(96, 4), 256, 0, stream>>>(
        X2, off_wT2, off_b, nullptr, nullptr, off_out, 448, 192, 189, 0, 0);

    // 3) tap table from off_out
    tap_prep<<<(BB_ * 63 * HWSZ + 255) / 256, 256, 0, stream>>>(off_out, idxT, wTab);

    // 4) DCN via MFMA + BN + ReLU + bz (consumes tap table + X2)
    dcn_bz_mfma<<<dim3(192, 4), 256, 0, stream>>>(
        X2, idxT, wTab, dcn_wA, dcn_b, bn_g, bn_be, bn_mn, bn_vr,
        bz_wb, bz_b, out_bz);
}